// Round 22
// baseline (447.568 us; speedup 1.0000x reference)
//
#include <hip/hip_runtime.h>

#define IC 4096
typedef unsigned short u16;
typedef unsigned int   u32;
typedef __fp16 h2 __attribute__((ext_vector_type(2)));   // cvt_pkrtz return type

static __device__ __forceinline__ u32 pack_rtz(float a, float b) {
    h2 h = __builtin_amdgcn_cvt_pkrtz(a, b);   // v_cvt_pkrtz_f16_f32
    u32 u; __builtin_memcpy(&u, &h, 4); return u;
}
static __device__ __forceinline__ float h2lo(u32 r) {
    h2 h; __builtin_memcpy(&h, &r, 4); return (float)h.x;
}
static __device__ __forceinline__ float h2hi(u32 r) {
    h2 h; __builtin_memcpy(&h, &r, 4); return (float)h.y;
}

// Barrier draining only lgkmcnt (r16: proven safe & neutral).
static __device__ __forceinline__ void barrier_lgkm() {
    asm volatile("s_waitcnt lgkmcnt(0)\n\ts_barrier" ::: "memory");
}

// DPP lane permute on the VALU pipe (r18/r19: -25% vs ds_bpermute softmax).
template<int CTRL>
static __device__ __forceinline__ float dppf(float x) {
    return __int_as_float(__builtin_amdgcn_update_dpp(
        0, __float_as_int(x), CTRL, 0xF, 0xF, true));
}

// ---------------- primary path: r19 structure with NB=8 phases ----------
// r21 evidence: USEV=0 (35% fewer VALU instr) == USEV=1 time -> per-phase
// machinery (barriers, W-remat L1 stream, reduce, partial store), not VALU
// count, is binding. NB=8 halves all of it: 16 phases x 8 b (was 32 x 4).
// Cost: LDS 64 KB -> 2 blocks/CU (A/B: machinery amortization vs occupancy).
// Everything else r19-verbatim. part column m holds (a,p) with
// m = (p>>1)*32 + a*2 + (p&1) -- inverted in squash (index math only).
template<int USEV>
__global__ __launch_bounds__(512)
void caps_pass_part(const float* __restrict__ x, const float* __restrict__ W,
                    const float* __restrict__ vprev, u32* __restrict__ part)
{
    __shared__ float lds[8][8][256];   // 64 KB
    const int tid  = threadIdx.x;
    const int wu   = __builtin_amdgcn_readfirstlane(tid >> 6);  // wave 0..7
    const int lane = tid & 63;
    const int a    = lane & 15;   // capsule 0..15  (row-of-16 position)
    const int dq   = lane >> 4;   // d-quad 0..3: lane owns d = dq*4..dq*4+3
    const int ib   = (int)blockIdx.x & 511;   // i-chunk
    const int bh   = (int)blockIdx.x >> 9;    // b-half
    const int i    = ib * 8 + wu;             // this wave's i

    float w[32];
    {
        const float* wp = W + ((size_t)a * IC + i) * 128 + dq * 32;
#pragma unroll
        for (int q = 0; q < 8; ++q) {
            const float4 f = *(const float4*)(wp + q * 4);
            w[q*4+0] = f.x; w[q*4+1] = f.y; w[q*4+2] = f.z; w[q*4+3] = f.w;
        }
    }
#pragma unroll
    for (int k = 0; k < 32; ++k) asm volatile("" : "+v"(w[k]));  // no remat

    const int b0 = bh * 128;
    const float SM_SCALE = 4096.0f * 1.44269504088896f;  // logits in log2 units
    const float* vbase = USEV ? (vprev + (size_t)b0 * 256 + a * 16 + dq * 4)
                              : nullptr;

    for (int ph = 0; ph < 16; ++ph) {
#pragma unroll
        for (int nb = 0; nb < 8; ++nb) {
            const int bl = ph * 8 + nb;     // local b 0..127
            const float* xp = x + ((size_t)(b0 + bl) * IC + i) * 8;
            const float4 xa = *(const float4*)(xp);
            const float4 xb = *(const float4*)(xp + 4);
            float4 va;
            if (USEV)
                va = *(const float4*)(vbase + (size_t)bl * 256);
            float u0, u1, u2, u3;
            u0 = xa.x * w[0];
            u1 = xa.x * w[8];
            u2 = xa.x * w[16];
            u3 = xa.x * w[24];
            u0 = fmaf(xa.y, w[1],  u0); u1 = fmaf(xa.y, w[9],  u1);
            u2 = fmaf(xa.y, w[17], u2); u3 = fmaf(xa.y, w[25], u3);
            u0 = fmaf(xa.z, w[2],  u0); u1 = fmaf(xa.z, w[10], u1);
            u2 = fmaf(xa.z, w[18], u2); u3 = fmaf(xa.z, w[26], u3);
            u0 = fmaf(xa.w, w[3],  u0); u1 = fmaf(xa.w, w[11], u1);
            u2 = fmaf(xa.w, w[19], u2); u3 = fmaf(xa.w, w[27], u3);
            u0 = fmaf(xb.x, w[4],  u0); u1 = fmaf(xb.x, w[12], u1);
            u2 = fmaf(xb.x, w[20], u2); u3 = fmaf(xb.x, w[28], u3);
            u0 = fmaf(xb.y, w[5],  u0); u1 = fmaf(xb.y, w[13], u1);
            u2 = fmaf(xb.y, w[21], u2); u3 = fmaf(xb.y, w[29], u3);
            u0 = fmaf(xb.z, w[6],  u0); u1 = fmaf(xb.z, w[14], u1);
            u2 = fmaf(xb.z, w[22], u2); u3 = fmaf(xb.z, w[30], u3);
            u0 = fmaf(xb.w, w[7],  u0); u1 = fmaf(xb.w, w[15], u1);
            u2 = fmaf(xb.w, w[23], u2); u3 = fmaf(xb.w, w[31], u3);
            float cw;
            if (USEV == 0) {
                cw = 1.0f / 16.0f;
            } else {
                // agree = u . vprev; combine the 4 d-quads (the only DS ops)
                float ag = u0 * va.x + u1 * va.y + u2 * va.z + u3 * va.w;
                ag += __shfl_xor(ag, 16);
                ag += __shfl_xor(ag, 32);
                const float blog2 = SM_SCALE * ag;
                // softmax over the 16-lane row, entirely on VALU DPP
                float m = blog2;
                m = fmaxf(m, dppf<0xB1>(m));    // quad_perm xor1
                m = fmaxf(m, dppf<0x4E>(m));    // quad_perm xor2
                m = fmaxf(m, dppf<0x124>(m));   // row_ror:4
                m = fmaxf(m, dppf<0x128>(m));   // row_ror:8
                const float e = __builtin_amdgcn_exp2f(blog2 - m);
                float sum = e;
                sum += dppf<0xB1>(sum);
                sum += dppf<0x4E>(sum);
                sum += dppf<0x124>(sum);
                sum += dppf<0x128>(sum);
                cw = __fdividef(e, sum);
            }
            // linear per-lane LDS write (b128, conflict-free, r19-proven)
            *(float4*)&lds[wu][nb][lane * 4] =
                make_float4(cw * u0, cw * u1, cw * u2, cw * u3);
        }
        barrier_lgkm();
        // reduce: thread = (nb = tid>>6, c4 = tid&63); float4 over 8 waves
        // at LINEAR offset c4*4 (conflict-free); coalesced uint2 store with
        // single fp16 RTZ rounding. Column semantics unchanged from r19.
        {
            const int nb = tid >> 6;      // 0..7
            const int c4 = tid & 63;      // float4 column
            float4 acc = make_float4(0.f, 0.f, 0.f, 0.f);
#pragma unroll
            for (int wv = 0; wv < 8; ++wv) {
                const float4 f = *(const float4*)&lds[wv][nb][c4 * 4];
                acc.x += f.x; acc.y += f.y; acc.z += f.z; acc.w += f.w;
            }
            const u32 p0 = pack_rtz(acc.x, acc.y);
            const u32 p1 = pack_rtz(acc.z, acc.w);
            *(uint2*)&part[(size_t)blockIdx.x * 16384
                           + (size_t)(ph * 8 + nb) * 128 + c4 * 2] =
                make_uint2(p0, p1);
        }
        barrier_lgkm();
    }
}

// Fused 512-deep partial reduction + squash. Thread = (b, r = a*8 + dpair):
// inverts the (a,p)->m layout permutation in index math only.
template<int ADDP>
__global__ __launch_bounds__(256)
void caps_squash_part(const u32* __restrict__ part, float* __restrict__ vout,
                      const float* __restrict__ vprev)
{
    const int gt = (int)blockIdx.x * 256 + (int)threadIdx.x;  // 0..32767
    const int b  = gt >> 7;
    const int r  = gt & 127;                                  // a*8 + dpair
    const int a  = r >> 3;
    const int p  = r & 7;
    const int m  = (p >> 1) * 32 + a * 2 + (p & 1);           // part column
    const int h  = b >> 7;                                    // b-half
    const int lb = b & 127;                                   // local b in tile
    const u32* pp = part + ((size_t)h * 512) * 16384 + (size_t)lb * 128 + m;
    float f0 = 0.f, f1 = 0.f;
#pragma unroll 8
    for (int ic = 0; ic < 512; ++ic) {
        const u32 raw = pp[(size_t)ic * 16384];
        f0 += h2lo(raw);
        f1 += h2hi(raw);
    }
    float sq = f0 * f0 + f1 * f1;
    sq += __shfl_xor(sq, 1);
    sq += __shfl_xor(sq, 2);
    sq += __shfl_xor(sq, 4);
    const float scale = sq / ((1.0f + sq) * sqrtf(sq + 1e-7f));
    float o0 = f0 * scale, o1 = f1 * scale;
    if (ADDP) {
        const float2 pv = *(const float2*)(vprev + (size_t)b * 256 + r * 2);
        o0 += pv.x; o1 += pv.y;
    }
    *(float2*)(vout + (size_t)b * 256 + r * 2) = make_float2(o0, o1);
}

// ---------------- fallback: r19 NB=4 path (known-good, 421.6 us) ----------
template<int USEV>
__global__ __launch_bounds__(512)
void caps_pass_nb4(const float* __restrict__ x, const float* __restrict__ W,
                   const float* __restrict__ vprev, u32* __restrict__ part)
{
    __shared__ float lds[8][4][256];
    const int tid  = threadIdx.x;
    const int wu   = __builtin_amdgcn_readfirstlane(tid >> 6);
    const int lane = tid & 63;
    const int a    = lane & 15;
    const int dq   = lane >> 4;
    const int ib   = (int)blockIdx.x & 511;
    const int bh   = (int)blockIdx.x >> 9;
    const int i    = ib * 8 + wu;

    float w[32];
    {
        const float* wp = W + ((size_t)a * IC + i) * 128 + dq * 32;
#pragma unroll
        for (int q = 0; q < 8; ++q) {
            const float4 f = *(const float4*)(wp + q * 4);
            w[q*4+0] = f.x; w[q*4+1] = f.y; w[q*4+2] = f.z; w[q*4+3] = f.w;
        }
    }
#pragma unroll
    for (int k = 0; k < 32; ++k) asm volatile("" : "+v"(w[k]));

    const int b0 = bh * 128;
    const float SM_SCALE = 4096.0f * 1.44269504088896f;
    const float* vbase = USEV ? (vprev + (size_t)b0 * 256 + a * 16 + dq * 4)
                              : nullptr;

    for (int ph = 0; ph < 32; ++ph) {
        float4 xa[4], xb[4], va[4];
        const float* xp0 = x + ((size_t)(b0 + ph * 4) * IC + i) * 8;
#pragma unroll
        for (int nb = 0; nb < 4; ++nb) {
            const float* xp = xp0 + (size_t)nb * IC * 8;
            xa[nb] = *(const float4*)(xp);
            xb[nb] = *(const float4*)(xp + 4);
            if (USEV)
                va[nb] = *(const float4*)(vbase + (size_t)(ph * 4 + nb) * 256);
        }
#pragma unroll
        for (int nb = 0; nb < 4; ++nb) {
            float u0, u1, u2, u3;
            u0 = xa[nb].x * w[0];
            u1 = xa[nb].x * w[8];
            u2 = xa[nb].x * w[16];
            u3 = xa[nb].x * w[24];
            u0 = fmaf(xa[nb].y, w[1],  u0); u1 = fmaf(xa[nb].y, w[9],  u1);
            u2 = fmaf(xa[nb].y, w[17], u2); u3 = fmaf(xa[nb].y, w[25], u3);
            u0 = fmaf(xa[nb].z, w[2],  u0); u1 = fmaf(xa[nb].z, w[10], u1);
            u2 = fmaf(xa[nb].z, w[18], u2); u3 = fmaf(xa[nb].z, w[26], u3);
            u0 = fmaf(xa[nb].w, w[3],  u0); u1 = fmaf(xa[nb].w, w[11], u1);
            u2 = fmaf(xa[nb].w, w[19], u2); u3 = fmaf(xa[nb].w, w[27], u3);
            u0 = fmaf(xb[nb].x, w[4],  u0); u1 = fmaf(xb[nb].x, w[12], u1);
            u2 = fmaf(xb[nb].x, w[20], u2); u3 = fmaf(xb[nb].x, w[28], u3);
            u0 = fmaf(xb[nb].y, w[5],  u0); u1 = fmaf(xb[nb].y, w[13], u1);
            u2 = fmaf(xb[nb].y, w[21], u2); u3 = fmaf(xb[nb].y, w[29], u3);
            u0 = fmaf(xb[nb].z, w[6],  u0); u1 = fmaf(xb[nb].z, w[14], u1);
            u2 = fmaf(xb[nb].z, w[22], u2); u3 = fmaf(xb[nb].z, w[30], u3);
            u0 = fmaf(xb[nb].w, w[7],  u0); u1 = fmaf(xb[nb].w, w[15], u1);
            u2 = fmaf(xb[nb].w, w[23], u2); u3 = fmaf(xb[nb].w, w[31], u3);
            float cw;
            if (USEV == 0) {
                cw = 1.0f / 16.0f;
            } else {
                float ag = u0 * va[nb].x + u1 * va[nb].y
                         + u2 * va[nb].z + u3 * va[nb].w;
                ag += __shfl_xor(ag, 16);
                ag += __shfl_xor(ag, 32);
                const float blog2 = SM_SCALE * ag;
                float m = blog2;
                m = fmaxf(m, dppf<0xB1>(m));
                m = fmaxf(m, dppf<0x4E>(m));
                m = fmaxf(m, dppf<0x124>(m));
                m = fmaxf(m, dppf<0x128>(m));
                const float e = __builtin_amdgcn_exp2f(blog2 - m);
                float sum = e;
                sum += dppf<0xB1>(sum);
                sum += dppf<0x4E>(sum);
                sum += dppf<0x124>(sum);
                sum += dppf<0x128>(sum);
                cw = __fdividef(e, sum);
            }
            *(float4*)&lds[wu][nb][lane * 4] =
                make_float4(cw * u0, cw * u1, cw * u2, cw * u3);
        }
        barrier_lgkm();
        {
            const int nb = tid >> 7;
            const int m  = tid & 127;
            float s0 = 0.f, s1 = 0.f;
#pragma unroll
            for (int wv = 0; wv < 8; ++wv) {
                const float2 f = *(const float2*)&lds[wv][nb][m * 2];
                s0 += f.x; s1 += f.y;
            }
            part[(size_t)blockIdx.x * 16384 + (size_t)(ph * 4 + nb) * 128 + m] =
                pack_rtz(s0, s1);
        }
        barrier_lgkm();
    }
}

extern "C" void kernel_launch(void* const* d_in, const int* in_sizes, int n_in,
                              void* d_out, int out_size, void* d_ws, size_t ws_size,
                              hipStream_t stream)
{
    const float* x = (const float*)d_in[0];   // [256, 4096, 8]
    const float* W = (const float*)d_in[1];   // [16, 4096, 16, 8]
    float* out = (float*)d_out;               // [256, 16, 16]

    // fp16 partials: 1024 tiles x 16384 u32 = 64 MiB
    const size_t need16 = (size_t)1024 * 16384 * 4 + 2 * 65536 * 4;
    if (ws_size < need16) return;   // harness guarantees ws; nb4 path needs same

    u32*  part = (u32*)d_ws;
    float* v1  = (float*)((char*)d_ws + (size_t)1024 * 16384 * 4);
    float* vs  = v1 + 65536;
    caps_pass_part<0><<<1024, 512, 0, stream>>>(x, W, nullptr, part);
    caps_squash_part<0><<<128, 256, 0, stream>>>(part, v1, nullptr);
    caps_pass_part<1><<<1024, 512, 0, stream>>>(x, W, v1, part);
    caps_squash_part<1><<<128, 256, 0, stream>>>(part, vs, v1);
    caps_pass_part<1><<<1024, 512, 0, stream>>>(x, W, vs, part);
    caps_squash_part<0><<<128, 256, 0, stream>>>(part, out, nullptr);
    (void)caps_pass_nb4<0>;  // r19 fallback retained for next-round restore
    (void)caps_pass_nb4<1>;
}

// Round 23
// 421.852 us; speedup vs baseline: 1.0610x; 1.0610x over previous
//
#include <hip/hip_runtime.h>

#define IC 4096
typedef unsigned short u16;
typedef unsigned int   u32;
typedef __fp16 h2 __attribute__((ext_vector_type(2)));   // cvt_pkrtz return type

static __device__ __forceinline__ u32 pack_rtz(float a, float b) {
    h2 h = __builtin_amdgcn_cvt_pkrtz(a, b);   // v_cvt_pkrtz_f16_f32
    u32 u; __builtin_memcpy(&u, &h, 4); return u;
}
static __device__ __forceinline__ float h2lo(u32 r) {
    h2 h; __builtin_memcpy(&h, &r, 4); return (float)h.x;
}
static __device__ __forceinline__ float h2hi(u32 r) {
    h2 h; __builtin_memcpy(&h, &r, 4); return (float)h.y;
}

// Barrier draining only lgkmcnt (r16: proven safe & neutral).
static __device__ __forceinline__ void barrier_lgkm() {
    asm volatile("s_waitcnt lgkmcnt(0)\n\ts_barrier" ::: "memory");
}

// DPP lane permute on the VALU pipe (r18/r19: -25% vs ds_bpermute softmax).
// CTRL: 0xB1 = quad_perm xor1, 0x4E = quad_perm xor2,
// 0x124 = row_ror:4, 0x128 = row_ror:8 (row = 16 lanes).
template<int CTRL>
static __device__ __forceinline__ float dppf(float x) {
    return __int_as_float(__builtin_amdgcn_update_dpp(
        0, __float_as_int(x), CTRL, 0xF, 0xF, true));
}

// ---------------- FINAL champion (r19/r21 structure, 421.6 us) ----------
// 22-round ledger: NB=4 phases, 512-thread blocks, DPP softmax (a=lane&15),
// linear conflict-free LDS reduce, permuted fp16 partial layout inverted in
// squash, lgkm-only barriers. Falsified alternatives: W residency, fp16/dot2
// contraction, pk_fma, NB=2/8, 256-thread blocks, vmcnt-drain theory.
// part column m holds (a,p) with m = (p>>1)*32 + a*2 + (p&1).
template<int USEV>
__global__ __launch_bounds__(512)
void caps_pass_part(const float* __restrict__ x, const float* __restrict__ W,
                    const float* __restrict__ vprev, u32* __restrict__ part)
{
    __shared__ float lds[8][4][256];
    const int tid  = threadIdx.x;
    const int wu   = __builtin_amdgcn_readfirstlane(tid >> 6);  // wave 0..7
    const int lane = tid & 63;
    const int a    = lane & 15;   // capsule 0..15  (row-of-16 position)
    const int dq   = lane >> 4;   // d-quad 0..3: lane owns d = dq*4..dq*4+3
    const int ib   = (int)blockIdx.x & 511;   // i-chunk
    const int bh   = (int)blockIdx.x >> 9;    // b-half
    const int i    = ib * 8 + wu;             // this wave's i

    float w[32];
    {
        const float* wp = W + ((size_t)a * IC + i) * 128 + dq * 32;
#pragma unroll
        for (int q = 0; q < 8; ++q) {
            const float4 f = *(const float4*)(wp + q * 4);
            w[q*4+0] = f.x; w[q*4+1] = f.y; w[q*4+2] = f.z; w[q*4+3] = f.w;
        }
    }
#pragma unroll
    for (int k = 0; k < 32; ++k) asm volatile("" : "+v"(w[k]));  // no remat

    const int b0 = bh * 128;
    const float SM_SCALE = 4096.0f * 1.44269504088896f;  // logits in log2 units
    const float* vbase = USEV ? (vprev + (size_t)b0 * 256 + a * 16 + dq * 4)
                              : nullptr;

    for (int ph = 0; ph < 32; ++ph) {
        float4 xa[4], xb[4], va[4];
        const float* xp0 = x + ((size_t)(b0 + ph * 4) * IC + i) * 8;
#pragma unroll
        for (int nb = 0; nb < 4; ++nb) {
            const float* xp = xp0 + (size_t)nb * IC * 8;
            xa[nb] = *(const float4*)(xp);
            xb[nb] = *(const float4*)(xp + 4);
            if (USEV)
                va[nb] = *(const float4*)(vbase + (size_t)(ph * 4 + nb) * 256);
        }
#pragma unroll
        for (int nb = 0; nb < 4; ++nb) {
            float u0, u1, u2, u3;
            u0 = xa[nb].x * w[0];
            u1 = xa[nb].x * w[8];
            u2 = xa[nb].x * w[16];
            u3 = xa[nb].x * w[24];
            u0 = fmaf(xa[nb].y, w[1],  u0); u1 = fmaf(xa[nb].y, w[9],  u1);
            u2 = fmaf(xa[nb].y, w[17], u2); u3 = fmaf(xa[nb].y, w[25], u3);
            u0 = fmaf(xa[nb].z, w[2],  u0); u1 = fmaf(xa[nb].z, w[10], u1);
            u2 = fmaf(xa[nb].z, w[18], u2); u3 = fmaf(xa[nb].z, w[26], u3);
            u0 = fmaf(xa[nb].w, w[3],  u0); u1 = fmaf(xa[nb].w, w[11], u1);
            u2 = fmaf(xa[nb].w, w[19], u2); u3 = fmaf(xa[nb].w, w[27], u3);
            u0 = fmaf(xb[nb].x, w[4],  u0); u1 = fmaf(xb[nb].x, w[12], u1);
            u2 = fmaf(xb[nb].x, w[20], u2); u3 = fmaf(xb[nb].x, w[28], u3);
            u0 = fmaf(xb[nb].y, w[5],  u0); u1 = fmaf(xb[nb].y, w[13], u1);
            u2 = fmaf(xb[nb].y, w[21], u2); u3 = fmaf(xb[nb].y, w[29], u3);
            u0 = fmaf(xb[nb].z, w[6],  u0); u1 = fmaf(xb[nb].z, w[14], u1);
            u2 = fmaf(xb[nb].z, w[22], u2); u3 = fmaf(xb[nb].z, w[30], u3);
            u0 = fmaf(xb[nb].w, w[7],  u0); u1 = fmaf(xb[nb].w, w[15], u1);
            u2 = fmaf(xb[nb].w, w[23], u2); u3 = fmaf(xb[nb].w, w[31], u3);
            float cw;
            if (USEV == 0) {
                cw = 1.0f / 16.0f;
            } else {
                // agree = u . vprev; combine the 4 d-quads (lanes a, a+16,
                // a+32, a+48) -- the only remaining DS ops (2 vs 10).
                float ag = u0 * va[nb].x + u1 * va[nb].y
                         + u2 * va[nb].z + u3 * va[nb].w;
                ag += __shfl_xor(ag, 16);
                ag += __shfl_xor(ag, 32);
                const float blog2 = SM_SCALE * ag;
                // softmax over the 16-lane row, entirely on VALU DPP
                float m = blog2;
                m = fmaxf(m, dppf<0xB1>(m));    // quad_perm xor1
                m = fmaxf(m, dppf<0x4E>(m));    // quad_perm xor2
                m = fmaxf(m, dppf<0x124>(m));   // row_ror:4
                m = fmaxf(m, dppf<0x128>(m));   // row_ror:8
                const float e = __builtin_amdgcn_exp2f(blog2 - m);
                float sum = e;
                sum += dppf<0xB1>(sum);
                sum += dppf<0x4E>(sum);
                sum += dppf<0x124>(sum);
                sum += dppf<0x128>(sum);
                cw = __fdividef(e, sum);
            }
            // linear per-lane LDS write (b128, conflict-free, r19-proven);
            // element order: float index = dq*64 + a*4 + j.
            *(float4*)&lds[wu][nb][lane * 4] =
                make_float4(cw * u0, cw * u1, cw * u2, cw * u3);
        }
        barrier_lgkm();
        // reduce: thread m = tid&127 reads LDS float2 at m*2 (LINEAR ->
        // conflict-free) and stores part column m (coalesced); single fp16
        // RTZ rounding at the store.
        {
            const int nb = tid >> 7;      // 0..3
            const int m  = tid & 127;     // linear float2 / output column
            float s0 = 0.f, s1 = 0.f;
#pragma unroll
            for (int wv = 0; wv < 8; ++wv) {
                const float2 f = *(const float2*)&lds[wv][nb][m * 2];
                s0 += f.x; s1 += f.y;
            }
            part[(size_t)blockIdx.x * 16384 + (size_t)(ph * 4 + nb) * 128 + m] =
                pack_rtz(s0, s1);
        }
        barrier_lgkm();
    }
}

// Fused 512-deep partial reduction + squash. Thread = (b, r = a*8 + dpair):
// inverts the (a,p)->m layout permutation in index math only.
template<int ADDP>
__global__ __launch_bounds__(256)
void caps_squash_part(const u32* __restrict__ part, float* __restrict__ vout,
                      const float* __restrict__ vprev)
{
    const int gt = (int)blockIdx.x * 256 + (int)threadIdx.x;  // 0..32767
    const int b  = gt >> 7;
    const int r  = gt & 127;                                  // a*8 + dpair
    const int a  = r >> 3;
    const int p  = r & 7;
    const int m  = (p >> 1) * 32 + a * 2 + (p & 1);           // part column
    const int h  = b >> 7;                                    // b-half
    const int lb = b & 127;                                   // local b in tile
    const u32* pp = part + ((size_t)h * 512) * 16384 + (size_t)lb * 128 + m;
    float f0 = 0.f, f1 = 0.f;
#pragma unroll 8
    for (int ic = 0; ic < 512; ++ic) {
        const u32 raw = pp[(size_t)ic * 16384];
        f0 += h2lo(raw);
        f1 += h2hi(raw);
    }
    float sq = f0 * f0 + f1 * f1;
    sq += __shfl_xor(sq, 1);
    sq += __shfl_xor(sq, 2);
    sq += __shfl_xor(sq, 4);
    const float scale = sq / ((1.0f + sq) * sqrtf(sq + 1e-7f));
    float o0 = f0 * scale, o1 = f1 * scale;
    if (ADDP) {
        const float2 pv = *(const float2*)(vprev + (size_t)b * 256 + r * 2);
        o0 += pv.x; o1 += pv.y;
    }
    *(float2*)(vout + (size_t)b * 256 + r * 2) = make_float2(o0, o1);
}

extern "C" void kernel_launch(void* const* d_in, const int* in_sizes, int n_in,
                              void* d_out, int out_size, void* d_ws, size_t ws_size,
                              hipStream_t stream)
{
    const float* x = (const float*)d_in[0];   // [256, 4096, 8]
    const float* W = (const float*)d_in[1];   // [16, 4096, 16, 8]
    float* out = (float*)d_out;               // [256, 16, 16]

    // fp16 partials: 1024 tiles x 16384 u32 = 64 MiB
    u32*  part = (u32*)d_ws;
    float* v1  = (float*)((char*)d_ws + (size_t)1024 * 16384 * 4);
    float* vs  = v1 + 65536;
    // iter 1: uniform coupling c = 1/16
    caps_pass_part<0><<<1024, 512, 0, stream>>>(x, W, nullptr, part);
    caps_squash_part<0><<<128, 256, 0, stream>>>(part, v1, nullptr);
    // iter 2: logits = IC * (u . v1)
    caps_pass_part<1><<<1024, 512, 0, stream>>>(x, W, v1, part);
    caps_squash_part<1><<<128, 256, 0, stream>>>(part, vs, v1);
    // iter 3: logits = IC * (u . (v1+v2))
    caps_pass_part<1><<<1024, 512, 0, stream>>>(x, W, vs, part);
    caps_squash_part<0><<<128, 256, 0, stream>>>(part, out, nullptr);
}